// Round 2
// baseline (2929.906 us; speedup 1.0000x reference)
//
#include <hip/hip_runtime.h>
#include <hip/hip_bf16.h>

// Problem: CausalMultiheadSelfAttention — B=2, S=2048, D=1024, H=16, dk=64
// Round 2: fp32 inputs/outputs (per reference dtype), bf16 intermediates in ws,
// fp32 accumulation everywhere. Same 5-kernel structure as R1.

#define BATCH   2
#define SEQLEN  2048
#define DMODEL  1024
#define NHEADS  16
#define DK      64

// ---- dtype helpers ----------------------------------------------------------
__device__ __forceinline__ float ldf(const float* p) { return *p; }
__device__ __forceinline__ float ldf(const __hip_bfloat16* p) { return __bfloat162float(*p); }
__device__ __forceinline__ void stf(float* p, float v) { *p = v; }
__device__ __forceinline__ void stf(__hip_bfloat16* p, float v) { *p = __float2bfloat16(v); }

// ---------------- GEMM: C[M,N] = A[M,K] @ W[N,K]^T, fp32 accum ---------------
#define TM 64
#define TN 64
#define TK 32

template <typename TA, typename TW, typename TC>
__global__ __launch_bounds__(256) void gemm_bt(
    const TA* __restrict__ A,
    const TW* __restrict__ W,
    TC* __restrict__ C,
    int M, int N, int K) {
  __shared__ float As[TM][TK + 1];
  __shared__ float Ws[TN][TK + 1];
  const int bm = blockIdx.x * TM;
  const int bn = blockIdx.y * TN;
  const int tx = threadIdx.x & 15;   // 0..15 -> N
  const int ty = threadIdx.x >> 4;   // 0..15 -> M
  float acc[4][4] = {};
  for (int k0 = 0; k0 < K; k0 += TK) {
    for (int i = threadIdx.x; i < TM * TK; i += 256) {
      int m = i / TK, kk = i % TK;
      As[m][kk] = ldf(&A[(size_t)(bm + m) * K + k0 + kk]);
      Ws[m][kk] = ldf(&W[(size_t)(bn + m) * K + k0 + kk]);
    }
    __syncthreads();
    for (int kk = 0; kk < TK; ++kk) {
      float a[4], w[4];
#pragma unroll
      for (int i = 0; i < 4; ++i) a[i] = As[ty + i * 16][kk];
#pragma unroll
      for (int j = 0; j < 4; ++j) w[j] = Ws[tx + j * 16][kk];
#pragma unroll
      for (int i = 0; i < 4; ++i)
#pragma unroll
        for (int j = 0; j < 4; ++j) acc[i][j] += a[i] * w[j];
    }
    __syncthreads();
  }
#pragma unroll
  for (int i = 0; i < 4; ++i)
#pragma unroll
    for (int j = 0; j < 4; ++j) {
      int m = bm + ty + i * 16, n = bn + tx + j * 16;
      stf(&C[(size_t)m * N + n], acc[i][j]);
    }
}

// ---------------- RoPE on Q and K, in place, [b,s,e] layout (bf16) -----------
__global__ __launch_bounds__(256) void rope_kernel(
    __hip_bfloat16* __restrict__ Q,
    __hip_bfloat16* __restrict__ Kt,
    const int* __restrict__ pos, int npairs) {
  int idx = blockIdx.x * blockDim.x + threadIdx.x;
  if (idx >= npairs) return;
  int ip = idx & 511;              // pair index within a row of 1024 (512 pairs)
  int s  = (idx >> 9) & (SEQLEN - 1);
  int p  = ip & 31;                // pair index within head (dk/2 = 32)
  // inv_freq = 10000^(-(2p)/64) = 2^(-log2(10000) * 2p/64)
  float inv_freq = exp2f(-13.287712379549449f * ((float)(2 * p) / 64.0f));
  float ang = (float)pos[s] * inv_freq;
  float sn, cs;
  sincosf(ang, &sn, &cs);
  size_t off = (size_t)idx * 2;
  float qe = __bfloat162float(Q[off]), qo = __bfloat162float(Q[off + 1]);
  Q[off]     = __float2bfloat16(qe * cs - qo * sn);
  Q[off + 1] = __float2bfloat16(qo * cs + qe * sn);
  float ke = __bfloat162float(Kt[off]), ko = __bfloat162float(Kt[off + 1]);
  Kt[off]     = __float2bfloat16(ke * cs - ko * sn);
  Kt[off + 1] = __float2bfloat16(ko * cs + ke * sn);
}

// ---------------- causal attention: 4 query rows per block (1 row / wave) ----
// Q,K,V,O all [b, s, h*64+d] (= [b,s,1024]) bf16.
__global__ __launch_bounds__(256) void attn_kernel(
    const __hip_bfloat16* __restrict__ Q,
    const __hip_bfloat16* __restrict__ K,
    const __hip_bfloat16* __restrict__ V,
    __hip_bfloat16* __restrict__ O) {
  __shared__ float kv[64][DK + 1];        // staged K tile, then V tiles
  __shared__ float qrow[4][DK];
  __shared__ float p[4][SEQLEN];          // scores then probabilities, per wave
  const int bh = blockIdx.y;              // 0..31
  const int b = bh / NHEADS, h = bh % NHEADS;
  const int q0 = blockIdx.x * 4;
  const int wave = threadIdx.x >> 6;
  const int lane = threadIdx.x & 63;
  const size_t base = ((size_t)b * SEQLEN) * DMODEL + (size_t)h * DK;

  // load the 4 query rows
  {
    int r = threadIdx.x / DK, d = threadIdx.x % DK;
    qrow[r][d] = __bfloat162float(Q[base + (size_t)(q0 + r) * DMODEL + d]);
  }
  __syncthreads();

  const int myq = q0 + wave;
  const int ntiles = (q0 + 3) / 64 + 1;
  const float NEG = -__builtin_inff();
  float mloc = NEG;

  // pass 1: scores into LDS, track max
  for (int t = 0; t < ntiles; ++t) {
    int j0 = t * 64;
    for (int i = threadIdx.x; i < 64 * DK; i += 256) {
      int r = i / DK, d = i % DK;
      kv[r][d] = __bfloat162float(K[base + (size_t)(j0 + r) * DMODEL + d]);
    }
    __syncthreads();
    int j = j0 + lane;
    float s_val;
    if (j <= myq) {
      float acc = 0.f;
#pragma unroll 8
      for (int d = 0; d < DK; ++d) acc += qrow[wave][d] * kv[lane][d];
      s_val = acc * 0.125f;   // 1/sqrt(64)
    } else {
      s_val = NEG;
    }
    p[wave][j0 + lane] = s_val;
    mloc = fmaxf(mloc, s_val);
    __syncthreads();
  }
  // wave-wide max
  for (int off = 32; off; off >>= 1) mloc = fmaxf(mloc, __shfl_xor(mloc, off, 64));
  // exp + sum
  float lsum = 0.f;
  for (int t = 0; t < ntiles; ++t) {
    float s_val = p[wave][t * 64 + lane];
    float e = (s_val == NEG) ? 0.f : __expf(s_val - mloc);
    p[wave][t * 64 + lane] = e;
    lsum += e;
  }
  for (int off = 32; off; off >>= 1) lsum += __shfl_xor(lsum, off, 64);
  float inv = 1.f / lsum;

  // pass 2: O[d=lane] = sum_j p_j * V[j][lane]
  float o = 0.f;
  for (int t = 0; t < ntiles; ++t) {
    int j0 = t * 64;
    for (int i = threadIdx.x; i < 64 * DK; i += 256) {
      int r = i / DK, d = i % DK;
      kv[r][d] = __bfloat162float(V[base + (size_t)(j0 + r) * DMODEL + d]);
    }
    __syncthreads();
#pragma unroll 8
    for (int j = 0; j < 64; ++j) o += p[wave][j0 + j] * kv[j][lane];
    __syncthreads();
  }
  o *= inv;
  O[base + (size_t)myq * DMODEL + lane] = __float2bfloat16(o);
}

// ---------------- launch -----------------------------------------------------
extern "C" void kernel_launch(void* const* d_in, const int* in_sizes, int n_in,
                              void* d_out, int out_size, void* d_ws, size_t ws_size,
                              hipStream_t stream) {
  const float* x  = (const float*)d_in[0];
  const float* Wq = (const float*)d_in[1];
  const float* Wk = (const float*)d_in[2];
  const float* Wv = (const float*)d_in[3];
  const float* Wo = (const float*)d_in[4];
  const int* pos  = (const int*)d_in[5];
  float* out = (float*)d_out;

  const size_t NELEM = (size_t)BATCH * SEQLEN * DMODEL;  // 4,194,304
  __hip_bfloat16* Qw = (__hip_bfloat16*)d_ws;
  __hip_bfloat16* Kw = Qw + NELEM;
  __hip_bfloat16* Vw = Kw + NELEM;
  __hip_bfloat16* Ow = Vw + NELEM;

  const int M = BATCH * SEQLEN;  // 4096
  dim3 ggrid(M / TM, DMODEL / TN);

  gemm_bt<float, float, __hip_bfloat16><<<ggrid, 256, 0, stream>>>(x, Wq, Qw, M, DMODEL, DMODEL);
  gemm_bt<float, float, __hip_bfloat16><<<ggrid, 256, 0, stream>>>(x, Wk, Kw, M, DMODEL, DMODEL);
  gemm_bt<float, float, __hip_bfloat16><<<ggrid, 256, 0, stream>>>(x, Wv, Vw, M, DMODEL, DMODEL);

  int npairs = BATCH * SEQLEN * (DMODEL / 2);  // 2,097,152
  rope_kernel<<<(npairs + 255) / 256, 256, 0, stream>>>(Qw, Kw, pos, npairs);

  attn_kernel<<<dim3(SEQLEN / 4, BATCH * NHEADS), 256, 0, stream>>>(Qw, Kw, Vw, Ow);

  gemm_bt<__hip_bfloat16, float, float><<<ggrid, 256, 0, stream>>>(Ow, Wo, out, M, DMODEL, DMODEL);
}

// Round 3
// 1415.056 us; speedup vs baseline: 2.0705x; 2.0705x over previous
//
#include <hip/hip_runtime.h>
#include <hip/hip_bf16.h>

// CausalMultiheadSelfAttention — B=2, S=2048, D=1024, H=16, dk=64
// R3: MFMA flash attention (16x16x32 bf16). GEMMs still vector fp32 (R4 target).
//  - V projection GEMM writes V transposed: Vt[b][h][dk][s]
//  - attention: per-wave 32-row Q strip, K/V frags direct from global (16B loads),
//    online softmax, P C-layout->A-layout via per-wave LDS, no barriers in K-loop.

#define BATCH   2
#define SEQLEN  2048
#define DMODEL  1024
#define NHEADS  16
#define DK      64

typedef __attribute__((ext_vector_type(8))) short bf16x8;
typedef __attribute__((ext_vector_type(4))) float f32x4;

// ---- dtype helpers ----------------------------------------------------------
__device__ __forceinline__ float ldf(const float* p) { return *p; }
__device__ __forceinline__ float ldf(const __hip_bfloat16* p) { return __bfloat162float(*p); }
__device__ __forceinline__ void stf(float* p, float v) { *p = v; }
__device__ __forceinline__ void stf(__hip_bfloat16* p, float v) { *p = __float2bfloat16(v); }

// ---------------- GEMM: C[M,N] = A[M,K] @ W[N,K]^T, fp32 accum ---------------
#define TM 64
#define TN 64
#define TK 32

template <typename TA, typename TW, typename TC, bool TRANS_V = false>
__global__ __launch_bounds__(256) void gemm_bt(
    const TA* __restrict__ A,
    const TW* __restrict__ W,
    TC* __restrict__ C,
    int M, int N, int K) {
  __shared__ float As[TM][TK + 1];
  __shared__ float Ws[TN][TK + 1];
  const int bm = blockIdx.x * TM;
  const int bn = blockIdx.y * TN;
  const int tx = threadIdx.x & 15;   // 0..15 -> N
  const int ty = threadIdx.x >> 4;   // 0..15 -> M
  float acc[4][4] = {};
  for (int k0 = 0; k0 < K; k0 += TK) {
    for (int i = threadIdx.x; i < TM * TK; i += 256) {
      int m = i / TK, kk = i % TK;
      As[m][kk] = ldf(&A[(size_t)(bm + m) * K + k0 + kk]);
      Ws[m][kk] = ldf(&W[(size_t)(bn + m) * K + k0 + kk]);
    }
    __syncthreads();
    for (int kk = 0; kk < TK; ++kk) {
      float a[4], w[4];
#pragma unroll
      for (int i = 0; i < 4; ++i) a[i] = As[ty + i * 16][kk];
#pragma unroll
      for (int j = 0; j < 4; ++j) w[j] = Ws[tx + j * 16][kk];
#pragma unroll
      for (int i = 0; i < 4; ++i)
#pragma unroll
        for (int j = 0; j < 4; ++j) acc[i][j] += a[i] * w[j];
    }
    __syncthreads();
  }
#pragma unroll
  for (int i = 0; i < 4; ++i)
#pragma unroll
    for (int j = 0; j < 4; ++j) {
      int m = bm + ty + i * 16, n = bn + tx + j * 16;
      if (TRANS_V) {
        // store to Vt[b][h][dk][s]: b=m>>11, s=m&2047, h=n>>6, dk=n&63
        size_t off = ((((size_t)(m >> 11) * NHEADS + (n >> 6)) * DK) + (n & 63)) * SEQLEN + (m & 2047);
        stf(&C[off], acc[i][j]);
      } else {
        stf(&C[(size_t)m * N + n], acc[i][j]);
      }
    }
}

// ---------------- RoPE on Q and K, in place, [b,s,e] layout (bf16) -----------
__global__ __launch_bounds__(256) void rope_kernel(
    __hip_bfloat16* __restrict__ Q,
    __hip_bfloat16* __restrict__ Kt,
    const int* __restrict__ pos, int npairs) {
  int idx = blockIdx.x * blockDim.x + threadIdx.x;
  if (idx >= npairs) return;
  int ip = idx & 511;              // pair index within a row of 1024 (512 pairs)
  int s  = (idx >> 9) & (SEQLEN - 1);
  int p  = ip & 31;                // pair index within head (dk/2 = 32)
  float inv_freq = exp2f(-13.287712379549449f * ((float)(2 * p) / 64.0f));
  float ang = (float)pos[s] * inv_freq;
  float sn, cs;
  sincosf(ang, &sn, &cs);
  size_t off = (size_t)idx * 2;
  float qe = __bfloat162float(Q[off]), qo = __bfloat162float(Q[off + 1]);
  Q[off]     = __float2bfloat16(qe * cs - qo * sn);
  Q[off + 1] = __float2bfloat16(qo * cs + qe * sn);
  float ke = __bfloat162float(Kt[off]), ko = __bfloat162float(Kt[off + 1]);
  Kt[off]     = __float2bfloat16(ke * cs - ko * sn);
  Kt[off + 1] = __float2bfloat16(ko * cs + ke * sn);
}

// ---------------- MFMA flash attention --------------------------------------
// Q,K,O: [b,s,1024] bf16 (head h at col h*64).  Vt: [b,h,64,2048] bf16.
// Block: 4 waves x 32 Q-rows = 128 rows. Grid: (16 q-blocks, 32 bh).
#define PSTR 72   // P LDS row stride in bf16: 144 B -> 16B-aligned rows, 2-way banks

__global__ __launch_bounds__(256) void attn_mfma(
    const __hip_bfloat16* __restrict__ Q,
    const __hip_bfloat16* __restrict__ K,
    const __hip_bfloat16* __restrict__ Vt,
    __hip_bfloat16* __restrict__ O) {
  __shared__ __align__(16) __hip_bfloat16 Pl[4][32][PSTR];   // per-wave P strip
  const int bh = blockIdx.y;
  const int b = bh >> 4, h = bh & 15;
  const int qb = (int)gridDim.x - 1 - (int)blockIdx.x;  // heavy blocks first
  const int q0 = qb * 128;
  const int wave = threadIdx.x >> 6;
  const int lane = threadIdx.x & 63;
  const int col = lane & 15;
  const int quad = lane >> 4;
  const int wrow0 = q0 + wave * 32;

  const size_t qkbase = ((size_t)b * SEQLEN) * DMODEL + (size_t)h * DK;
  const size_t vbase  = (size_t)bh * DK * SEQLEN;

  // Q fragments (A-layout): qf[mt][kc], row = wrow0 + mt*16 + col, k = kc*32+quad*8+j
  bf16x8 qf[2][2];
#pragma unroll
  for (int mt = 0; mt < 2; ++mt)
#pragma unroll
    for (int kc = 0; kc < 2; ++kc)
      qf[mt][kc] = *(const bf16x8*)(Q + qkbase +
          (size_t)(wrow0 + mt * 16 + col) * DMODEL + kc * 32 + quad * 8);

  f32x4 acc[2][4] = {};       // O accumulator [mt][dt], C-layout
  float m_i[2][4], l_i[2][4];
#pragma unroll
  for (int mt = 0; mt < 2; ++mt)
#pragma unroll
    for (int r = 0; r < 4; ++r) { m_i[mt][r] = -1e30f; l_i[mt][r] = 0.f; }

  const int ntiles = q0 / 64 + 2;   // keys 0 .. q0+127
  for (int t = 0; t < ntiles; ++t) {
    const int j0 = t * 64;

    // ---- S = Q K^T for this 64-key tile (per-wave: 32x64) ----
    f32x4 s[2][4] = {};
#pragma unroll
    for (int nt = 0; nt < 4; ++nt)
#pragma unroll
      for (int kc = 0; kc < 2; ++kc) {
        bf16x8 kf = *(const bf16x8*)(K + qkbase +
            (size_t)(j0 + nt * 16 + col) * DMODEL + kc * 32 + quad * 8);
#pragma unroll
        for (int mt = 0; mt < 2; ++mt)
          s[mt][nt] = __builtin_amdgcn_mfma_f32_16x16x32_bf16(qf[mt][kc], kf, s[mt][nt], 0, 0, 0);
      }

    const bool diag = (j0 + 63) > wrow0;

    // ---- online softmax (row = quad*4 + r within 16-tile; reduce over 16 lanes) ----
#pragma unroll
    for (int mt = 0; mt < 2; ++mt)
#pragma unroll
      for (int r = 0; r < 4; ++r) {
        const int qr = wrow0 + mt * 16 + quad * 4 + r;
        float mx = m_i[mt][r];
#pragma unroll
        for (int nt = 0; nt < 4; ++nt) {
          float sv = s[mt][nt][r] * 0.125f;
          if (diag && (j0 + nt * 16 + col) > qr) sv = -1e30f;
          mx = fmaxf(mx, sv);
        }
        mx = fmaxf(mx, __shfl_xor(mx, 1, 64));
        mx = fmaxf(mx, __shfl_xor(mx, 2, 64));
        mx = fmaxf(mx, __shfl_xor(mx, 4, 64));
        mx = fmaxf(mx, __shfl_xor(mx, 8, 64));
        float alpha = __expf(m_i[mt][r] - mx);
        m_i[mt][r] = mx;
        float rs = 0.f;
#pragma unroll
        for (int nt = 0; nt < 4; ++nt) {
          float sv = s[mt][nt][r] * 0.125f;
          if (diag && (j0 + nt * 16 + col) > qr) sv = -1e30f;
          float pv = __expf(sv - mx);
          rs += pv;
          Pl[wave][mt * 16 + quad * 4 + r][nt * 16 + col] = __float2bfloat16(pv);
        }
        rs += __shfl_xor(rs, 1, 64);
        rs += __shfl_xor(rs, 2, 64);
        rs += __shfl_xor(rs, 4, 64);
        rs += __shfl_xor(rs, 8, 64);
        l_i[mt][r] = l_i[mt][r] * alpha + rs;
#pragma unroll
        for (int dt = 0; dt < 4; ++dt) acc[mt][dt][r] *= alpha;
      }

    // ---- O += P V  (P A-frags from LDS, V B-frags direct from global Vt) ----
#pragma unroll
    for (int jc = 0; jc < 2; ++jc) {
      bf16x8 pf[2];
#pragma unroll
      for (int mt = 0; mt < 2; ++mt)
        pf[mt] = *(const bf16x8*)&Pl[wave][mt * 16 + col][jc * 32 + quad * 8];
#pragma unroll
      for (int dt = 0; dt < 4; ++dt) {
        bf16x8 vf = *(const bf16x8*)(Vt + vbase +
            (size_t)(dt * 16 + col) * SEQLEN + j0 + jc * 32 + quad * 8);
#pragma unroll
        for (int mt = 0; mt < 2; ++mt)
          acc[mt][dt] = __builtin_amdgcn_mfma_f32_16x16x32_bf16(pf[mt], vf, acc[mt][dt], 0, 0, 0);
      }
    }
  }

  // ---- epilogue: O = acc / l ----
#pragma unroll
  for (int mt = 0; mt < 2; ++mt)
#pragma unroll
    for (int r = 0; r < 4; ++r) {
      float inv = 1.f / l_i[mt][r];
      const size_t row = qkbase + (size_t)(wrow0 + mt * 16 + quad * 4 + r) * DMODEL;
#pragma unroll
      for (int dt = 0; dt < 4; ++dt)
        O[row + dt * 16 + col] = __float2bfloat16(acc[mt][dt][r] * inv);
    }
}

// ---------------- launch -----------------------------------------------------
extern "C" void kernel_launch(void* const* d_in, const int* in_sizes, int n_in,
                              void* d_out, int out_size, void* d_ws, size_t ws_size,
                              hipStream_t stream) {
  const float* x  = (const float*)d_in[0];
  const float* Wq = (const float*)d_in[1];
  const float* Wk = (const float*)d_in[2];
  const float* Wv = (const float*)d_in[3];
  const float* Wo = (const float*)d_in[4];
  const int* pos  = (const int*)d_in[5];
  float* out = (float*)d_out;

  const size_t NELEM = (size_t)BATCH * SEQLEN * DMODEL;  // 4,194,304
  __hip_bfloat16* Qw  = (__hip_bfloat16*)d_ws;
  __hip_bfloat16* Kw  = Qw + NELEM;
  __hip_bfloat16* Vtw = Kw + NELEM;     // [b][h][dk][s]
  __hip_bfloat16* Ow  = Vtw + NELEM;

  const int M = BATCH * SEQLEN;  // 4096
  dim3 ggrid(M / TM, DMODEL / TN);

  gemm_bt<float, float, __hip_bfloat16, false><<<ggrid, 256, 0, stream>>>(x, Wq, Qw, M, DMODEL, DMODEL);
  gemm_bt<float, float, __hip_bfloat16, false><<<ggrid, 256, 0, stream>>>(x, Wk, Kw, M, DMODEL, DMODEL);
  gemm_bt<float, float, __hip_bfloat16, true ><<<ggrid, 256, 0, stream>>>(x, Wv, Vtw, M, DMODEL, DMODEL);

  int npairs = BATCH * SEQLEN * (DMODEL / 2);
  rope_kernel<<<(npairs + 255) / 256, 256, 0, stream>>>(Qw, Kw, pos, npairs);

  attn_mfma<<<dim3(16, BATCH * NHEADS), 256, 0, stream>>>(Qw, Kw, Vtw, Ow);

  gemm_bt<__hip_bfloat16, float, float, false><<<ggrid, 256, 0, stream>>>(Ow, Wo, out, M, DMODEL, DMODEL);
}

// Round 4
// 363.408 us; speedup vs baseline: 8.0623x; 3.8939x over previous
//
#include <hip/hip_runtime.h>
#include <hip/hip_bf16.h>

// CausalMultiheadSelfAttention — B=2, S=2048, D=1024, H=16, dk=64
// R4: MFMA everywhere. cast(fp32->bf16) -> fused QKV MFMA GEMM (V transposed)
//     -> RoPE -> MFMA flash attention -> MFMA out-proj (fp32 store).

#define BATCH   2
#define SEQLEN  2048
#define DMODEL  1024
#define NHEADS  16
#define DK      64

typedef __attribute__((ext_vector_type(8))) short bf16x8;
typedef __attribute__((ext_vector_type(4))) short bf16x4;
typedef __attribute__((ext_vector_type(4))) float f32x4;

__device__ __forceinline__ void gload_lds16(const void* g, void* l) {
  __builtin_amdgcn_global_load_lds(
      (const __attribute__((address_space(1))) unsigned int*)g,
      (__attribute__((address_space(3))) unsigned int*)l, 16, 0, 0);
}

// ---------------- cast fp32 -> bf16: x (4M) + Wq/Wk/Wv/Wo (1M each) ----------
__global__ __launch_bounds__(256) void cast_all(
    const float* __restrict__ x,  const float* __restrict__ wq,
    const float* __restrict__ wk, const float* __restrict__ wv,
    const float* __restrict__ wo,
    __hip_bfloat16* __restrict__ xb,  __hip_bfloat16* __restrict__ wqb,
    __hip_bfloat16* __restrict__ wkb, __hip_bfloat16* __restrict__ wvb,
    __hip_bfloat16* __restrict__ wob) {
  const size_t MM = (size_t)1 << 20;
  size_t i = ((size_t)blockIdx.x * 256 + threadIdx.x) * 8;
  const float* src; __hip_bfloat16* dst; size_t off = i;
  if (i < 4 * MM)      { src = x;  dst = xb; }
  else if (i < 5 * MM) { src = wq; dst = wqb; off = i - 4 * MM; }
  else if (i < 6 * MM) { src = wk; dst = wkb; off = i - 5 * MM; }
  else if (i < 7 * MM) { src = wv; dst = wvb; off = i - 6 * MM; }
  else                 { src = wo; dst = wob; off = i - 7 * MM; }
  float4 a = *(const float4*)(src + off);
  float4 b = *(const float4*)(src + off + 4);
  __hip_bfloat16 t[8];
  t[0] = __float2bfloat16(a.x); t[1] = __float2bfloat16(a.y);
  t[2] = __float2bfloat16(a.z); t[3] = __float2bfloat16(a.w);
  t[4] = __float2bfloat16(b.x); t[5] = __float2bfloat16(b.y);
  t[6] = __float2bfloat16(b.z); t[7] = __float2bfloat16(b.w);
  *(bf16x8*)(dst + off) = *(const bf16x8*)t;
}

// ---------------- MFMA GEMM core: 128x128 tile, BK=32, 4 waves x 64x64 ------
// A[M][K], W[N][K] bf16 (K-contiguous). acc[mt][nt] C-layout.
// LDS: [row][chunk] with chunk slot XOR-swizzled by (row&3); staged via
// global_load_lds width=16 (wave-uniform LDS base + lane*16).
__device__ __forceinline__ void gemm_core(
    const __hip_bfloat16* __restrict__ A, const __hip_bfloat16* __restrict__ W,
    int bm, int bn, int K, f32x4 (&acc)[4][4]) {
  __shared__ __hip_bfloat16 As[128 * 32];
  __shared__ __hip_bfloat16 Ws[128 * 32];
  const int tid  = threadIdx.x;
  const int wave = tid >> 6, lane = tid & 63;
  const int col  = lane & 15, quad = lane >> 4;
  const int wm   = (wave & 1) * 64, wn = (wave >> 1) * 64;
  const int srow = wave * 32;            // rows this wave stages
  const int l4   = lane >> 2, sl = lane & 3;

  for (int k0 = 0; k0 < K; k0 += 32) {
#pragma unroll
    for (int c = 0; c < 2; ++c) {
      int r = srow + c * 16 + l4;        // tile-local row
      int g = sl ^ (r & 3);              // swizzled global chunk for this slot
      gload_lds16(A + (size_t)(bm + r) * K + k0 + g * 8, &As[(srow + c * 16) * 32]);
      gload_lds16(W + (size_t)(bn + r) * K + k0 + g * 8, &Ws[(srow + c * 16) * 32]);
    }
    __syncthreads();
    bf16x8 af[4], bfr[4];
#pragma unroll
    for (int mt = 0; mt < 4; ++mt) {
      int r = wm + mt * 16 + col;
      af[mt] = *(const bf16x8*)&As[r * 32 + ((quad ^ (r & 3)) * 8)];
    }
#pragma unroll
    for (int nt = 0; nt < 4; ++nt) {
      int r = wn + nt * 16 + col;
      bfr[nt] = *(const bf16x8*)&Ws[r * 32 + ((quad ^ (r & 3)) * 8)];
    }
#pragma unroll
    for (int mt = 0; mt < 4; ++mt)
#pragma unroll
      for (int nt = 0; nt < 4; ++nt)
        acc[mt][nt] = __builtin_amdgcn_mfma_f32_16x16x32_bf16(af[mt], bfr[nt], acc[mt][nt], 0, 0, 0);
    __syncthreads();
  }
}

// ---------------- fused QKV GEMM (z: 0=Q, 1=K, 2=V-transposed) ---------------
__global__ __launch_bounds__(256) void mfma_qkv(
    const __hip_bfloat16* __restrict__ xb,
    const __hip_bfloat16* __restrict__ wqb,
    const __hip_bfloat16* __restrict__ wkb,
    const __hip_bfloat16* __restrict__ wvb,
    __hip_bfloat16* __restrict__ Qw,
    __hip_bfloat16* __restrict__ Kw,
    __hip_bfloat16* __restrict__ Vtw) {
  const int z = blockIdx.z;
  const __hip_bfloat16* W = (z == 0) ? wqb : (z == 1) ? wkb : wvb;
  const int bm = blockIdx.x * 128, bn = blockIdx.y * 128;
  f32x4 acc[4][4] = {};
  gemm_core(xb, W, bm, bn, DMODEL, acc);

  const int wave = threadIdx.x >> 6, lane = threadIdx.x & 63;
  const int col  = lane & 15, quad = lane >> 4;
  const int wm   = (wave & 1) * 64, wn = (wave >> 1) * 64;

  if (z < 2) {
    __hip_bfloat16* C = (z == 0) ? Qw : Kw;
#pragma unroll
    for (int mt = 0; mt < 4; ++mt)
#pragma unroll
      for (int nt = 0; nt < 4; ++nt) {
        int n = bn + wn + nt * 16 + col;
#pragma unroll
        for (int r = 0; r < 4; ++r) {
          int m = bm + wm + mt * 16 + quad * 4 + r;
          C[(size_t)m * DMODEL + n] = __float2bfloat16(acc[mt][nt][r]);
        }
      }
  } else {
    // Vt[b][h][dk][s]; pack 4 consecutive s per lane (8B store)
#pragma unroll
    for (int mt = 0; mt < 4; ++mt)
#pragma unroll
      for (int nt = 0; nt < 4; ++nt) {
        int n  = bn + wn + nt * 16 + col;          // h = n>>6, dk = n&63
        int m0 = bm + wm + mt * 16 + quad * 4;     // b = m0>>11, s = m0&2047
        __hip_bfloat16 t[4];
#pragma unroll
        for (int r = 0; r < 4; ++r) t[r] = __float2bfloat16(acc[mt][nt][r]);
        size_t off = (((size_t)(m0 >> 11) * NHEADS + (n >> 6)) * DK + (n & 63)) * SEQLEN + (m0 & 2047);
        *(bf16x4*)(Vtw + off) = *(const bf16x4*)t;
      }
  }
}

// ---------------- out-projection GEMM: fp32 store to d_out -------------------
__global__ __launch_bounds__(256) void mfma_out(
    const __hip_bfloat16* __restrict__ Ow,
    const __hip_bfloat16* __restrict__ wob,
    float* __restrict__ out) {
  const int bm = blockIdx.x * 128, bn = blockIdx.y * 128;
  f32x4 acc[4][4] = {};
  gemm_core(Ow, wob, bm, bn, DMODEL, acc);
  const int wave = threadIdx.x >> 6, lane = threadIdx.x & 63;
  const int col  = lane & 15, quad = lane >> 4;
  const int wm   = (wave & 1) * 64, wn = (wave >> 1) * 64;
#pragma unroll
  for (int mt = 0; mt < 4; ++mt)
#pragma unroll
    for (int nt = 0; nt < 4; ++nt) {
      int n = bn + wn + nt * 16 + col;
#pragma unroll
      for (int r = 0; r < 4; ++r) {
        int m = bm + wm + mt * 16 + quad * 4 + r;
        out[(size_t)m * DMODEL + n] = acc[mt][nt][r];
      }
    }
}

// ---------------- RoPE on Q and K, in place, [b,s,e] layout (bf16) -----------
__global__ __launch_bounds__(256) void rope_kernel(
    __hip_bfloat16* __restrict__ Q,
    __hip_bfloat16* __restrict__ Kt,
    const int* __restrict__ pos, int npairs) {
  int idx = blockIdx.x * blockDim.x + threadIdx.x;
  if (idx >= npairs) return;
  int ip = idx & 511;
  int s  = (idx >> 9) & (SEQLEN - 1);
  int p  = ip & 31;
  float inv_freq = exp2f(-13.287712379549449f * ((float)(2 * p) / 64.0f));
  float ang = (float)pos[s] * inv_freq;
  float sn, cs;
  sincosf(ang, &sn, &cs);
  size_t off = (size_t)idx * 2;
  float qe = __bfloat162float(Q[off]), qo = __bfloat162float(Q[off + 1]);
  Q[off]     = __float2bfloat16(qe * cs - qo * sn);
  Q[off + 1] = __float2bfloat16(qo * cs + qe * sn);
  float ke = __bfloat162float(Kt[off]), ko = __bfloat162float(Kt[off + 1]);
  Kt[off]     = __float2bfloat16(ke * cs - ko * sn);
  Kt[off + 1] = __float2bfloat16(ko * cs + ke * sn);
}

// ---------------- MFMA flash attention (unchanged from R3) -------------------
#define PSTR 72

__global__ __launch_bounds__(256) void attn_mfma(
    const __hip_bfloat16* __restrict__ Q,
    const __hip_bfloat16* __restrict__ K,
    const __hip_bfloat16* __restrict__ Vt,
    __hip_bfloat16* __restrict__ O) {
  __shared__ __align__(16) __hip_bfloat16 Pl[4][32][PSTR];
  const int bh = blockIdx.y;
  const int b = bh >> 4, h = bh & 15;
  const int qb = (int)gridDim.x - 1 - (int)blockIdx.x;
  const int q0 = qb * 128;
  const int wave = threadIdx.x >> 6;
  const int lane = threadIdx.x & 63;
  const int col = lane & 15;
  const int quad = lane >> 4;
  const int wrow0 = q0 + wave * 32;

  const size_t qkbase = ((size_t)b * SEQLEN) * DMODEL + (size_t)h * DK;
  const size_t vbase  = (size_t)bh * DK * SEQLEN;

  bf16x8 qf[2][2];
#pragma unroll
  for (int mt = 0; mt < 2; ++mt)
#pragma unroll
    for (int kc = 0; kc < 2; ++kc)
      qf[mt][kc] = *(const bf16x8*)(Q + qkbase +
          (size_t)(wrow0 + mt * 16 + col) * DMODEL + kc * 32 + quad * 8);

  f32x4 acc[2][4] = {};
  float m_i[2][4], l_i[2][4];
#pragma unroll
  for (int mt = 0; mt < 2; ++mt)
#pragma unroll
    for (int r = 0; r < 4; ++r) { m_i[mt][r] = -1e30f; l_i[mt][r] = 0.f; }

  const int ntiles = q0 / 64 + 2;
  for (int t = 0; t < ntiles; ++t) {
    const int j0 = t * 64;
    f32x4 s[2][4] = {};
#pragma unroll
    for (int nt = 0; nt < 4; ++nt)
#pragma unroll
      for (int kc = 0; kc < 2; ++kc) {
        bf16x8 kf = *(const bf16x8*)(K + qkbase +
            (size_t)(j0 + nt * 16 + col) * DMODEL + kc * 32 + quad * 8);
#pragma unroll
        for (int mt = 0; mt < 2; ++mt)
          s[mt][nt] = __builtin_amdgcn_mfma_f32_16x16x32_bf16(qf[mt][kc], kf, s[mt][nt], 0, 0, 0);
      }

    const bool diag = (j0 + 63) > wrow0;

#pragma unroll
    for (int mt = 0; mt < 2; ++mt)
#pragma unroll
      for (int r = 0; r < 4; ++r) {
        const int qr = wrow0 + mt * 16 + quad * 4 + r;
        float mx = m_i[mt][r];
#pragma unroll
        for (int nt = 0; nt < 4; ++nt) {
          float sv = s[mt][nt][r] * 0.125f;
          if (diag && (j0 + nt * 16 + col) > qr) sv = -1e30f;
          mx = fmaxf(mx, sv);
        }
        mx = fmaxf(mx, __shfl_xor(mx, 1, 64));
        mx = fmaxf(mx, __shfl_xor(mx, 2, 64));
        mx = fmaxf(mx, __shfl_xor(mx, 4, 64));
        mx = fmaxf(mx, __shfl_xor(mx, 8, 64));
        float alpha = __expf(m_i[mt][r] - mx);
        m_i[mt][r] = mx;
        float rs = 0.f;
#pragma unroll
        for (int nt = 0; nt < 4; ++nt) {
          float sv = s[mt][nt][r] * 0.125f;
          if (diag && (j0 + nt * 16 + col) > qr) sv = -1e30f;
          float pv = __expf(sv - mx);
          rs += pv;
          Pl[wave][mt * 16 + quad * 4 + r][nt * 16 + col] = __float2bfloat16(pv);
        }
        rs += __shfl_xor(rs, 1, 64);
        rs += __shfl_xor(rs, 2, 64);
        rs += __shfl_xor(rs, 4, 64);
        rs += __shfl_xor(rs, 8, 64);
        l_i[mt][r] = l_i[mt][r] * alpha + rs;
#pragma unroll
        for (int dt = 0; dt < 4; ++dt) acc[mt][dt][r] *= alpha;
      }

#pragma unroll
    for (int jc = 0; jc < 2; ++jc) {
      bf16x8 pf[2];
#pragma unroll
      for (int mt = 0; mt < 2; ++mt)
        pf[mt] = *(const bf16x8*)&Pl[wave][mt * 16 + col][jc * 32 + quad * 8];
#pragma unroll
      for (int dt = 0; dt < 4; ++dt) {
        bf16x8 vf = *(const bf16x8*)(Vt + vbase +
            (size_t)(dt * 16 + col) * SEQLEN + j0 + jc * 32 + quad * 8);
#pragma unroll
        for (int mt = 0; mt < 2; ++mt)
          acc[mt][dt] = __builtin_amdgcn_mfma_f32_16x16x32_bf16(pf[mt], vf, acc[mt][dt], 0, 0, 0);
      }
    }
  }

#pragma unroll
  for (int mt = 0; mt < 2; ++mt)
#pragma unroll
    for (int r = 0; r < 4; ++r) {
      float inv = 1.f / l_i[mt][r];
      const size_t row = qkbase + (size_t)(wrow0 + mt * 16 + quad * 4 + r) * DMODEL;
#pragma unroll
      for (int dt = 0; dt < 4; ++dt)
        O[row + dt * 16 + col] = __float2bfloat16(acc[mt][dt][r] * inv);
    }
}

// ---------------- launch -----------------------------------------------------
extern "C" void kernel_launch(void* const* d_in, const int* in_sizes, int n_in,
                              void* d_out, int out_size, void* d_ws, size_t ws_size,
                              hipStream_t stream) {
  const float* x  = (const float*)d_in[0];
  const float* Wq = (const float*)d_in[1];
  const float* Wk = (const float*)d_in[2];
  const float* Wv = (const float*)d_in[3];
  const float* Wo = (const float*)d_in[4];
  const int* pos  = (const int*)d_in[5];
  float* out = (float*)d_out;

  const size_t NELEM = (size_t)BATCH * SEQLEN * DMODEL;  // 4 Mi
  const size_t WELEM = (size_t)DMODEL * DMODEL;          // 1 Mi
  __hip_bfloat16* xb  = (__hip_bfloat16*)d_ws;           // 8 MB; Ow aliases after QKV
  __hip_bfloat16* Qw  = xb + NELEM;
  __hip_bfloat16* Kw  = Qw + NELEM;
  __hip_bfloat16* Vtw = Kw + NELEM;                      // [b][h][dk][s]
  __hip_bfloat16* wqb = Vtw + NELEM;
  __hip_bfloat16* wkb = wqb + WELEM;
  __hip_bfloat16* wvb = wkb + WELEM;
  __hip_bfloat16* wob = wvb + WELEM;
  __hip_bfloat16* Ow  = xb;   // alias: xb dead after QKV GEMM

  cast_all<<<4096, 256, 0, stream>>>(x, Wq, Wk, Wv, Wo, xb, wqb, wkb, wvb, wob);

  mfma_qkv<<<dim3(32, 8, 3), 256, 0, stream>>>(xb, wqb, wkb, wvb, Qw, Kw, Vtw);

  int npairs = BATCH * SEQLEN * (DMODEL / 2);
  rope_kernel<<<(npairs + 255) / 256, 256, 0, stream>>>(Qw, Kw, pos, npairs);

  attn_mfma<<<dim3(16, BATCH * NHEADS), 256, 0, stream>>>(Qw, Kw, Vtw, Ow);

  mfma_out<<<dim3(32, 8), 256, 0, stream>>>(Ow, wob, out);
}